// Round 1
// baseline (308.559 us; speedup 1.0000x reference)
//
#include <hip/hip_runtime.h>
#include <stdint.h>

#define N_NODES 50000
#define N_EDGES 600000
#define DIM 128

// ---- workspace layout (bytes) ----
#define WS_CNT     0            // 50000 * 4
#define WS_OFF     204800       // 50001 * 4
#define WS_CUR     409600       // 50000 * 4
#define WS_CSR     614400       // 600000 * 4
#define WS_BFRAG   3014656      // 2 * 16384 shorts = 65536 B (self, then neigh)
#define WS_BIAS    3080192      // 128 * 4
#define WS_AGG     3080704      // 50000*128*4 = 25.6 MB
// total ~28.7 MB

typedef __attribute__((ext_vector_type(8))) short short8;
typedef __attribute__((ext_vector_type(4))) float floatx4;

__device__ __forceinline__ short f2bf(float f) {
    union { float f; uint32_t u; } x; x.f = f;
    uint32_t r = x.u + 0x7fffu + ((x.u >> 16) & 1u);   // round-to-nearest-even
    return (short)(r >> 16);
}

// ---------------- prep: zero counts, swizzle weights to B-fragment order, bias sum
__global__ void k_prep(const float* __restrict__ Wself,
                       const float* __restrict__ Wneigh,
                       const float* __restrict__ bself,
                       const float* __restrict__ bneigh,
                       int* __restrict__ cnt,
                       short* __restrict__ bfrag,
                       float* __restrict__ biasSum) {
    int id = blockIdx.x * blockDim.x + threadIdx.x;
    if (id < N_NODES) cnt[id] = 0;
    int wid = id - N_NODES;
    if (wid >= 0 && wid < 4096) {
        // fragment layout: ((t*4 + c)*64 + lane)*8 + j  holds  W[c*32 + (lane>>4)*8 + j][t*16 + (lane&15)]
        int w    = wid >> 11;          // 0 = self, 1 = neigh
        int fi   = wid & 2047;
        int lane = fi & 63;
        int tc   = fi >> 6;
        int c    = tc & 3, t = tc >> 2;
        const float* W = w ? Wneigh : Wself;
        int kbase = c * 32 + (lane >> 4) * 8;
        int n     = t * 16 + (lane & 15);
        short* dst = bfrag + (size_t)wid * 8;
        #pragma unroll
        for (int j = 0; j < 8; ++j) dst[j] = f2bf(W[(kbase + j) * DIM + n]);
    }
    int bid = id - N_NODES - 4096;
    if (bid >= 0 && bid < DIM) biasSum[bid] = bself[bid] + bneigh[bid];
}

// ---------------- count in-degree (excluding self loops)
__global__ void k_count(const int* __restrict__ dst, int* __restrict__ cnt) {
    int e = blockIdx.x * blockDim.x + threadIdx.x;
    if (e < N_EDGES) atomicAdd(&cnt[dst[e]], 1);
}

// ---------------- single-block exclusive scan -> offsets + cursor
#define SCAN_T 1024
#define CHUNK  49   // ceil(50000/1024)
__global__ __launch_bounds__(SCAN_T) void k_scan(const int* __restrict__ cnt,
                                                 int* __restrict__ off,
                                                 int* __restrict__ cur) {
    __shared__ int s[SCAN_T];
    int t  = threadIdx.x;
    int lo = t * CHUNK;
    int hi = lo + CHUNK; if (hi > N_NODES) hi = N_NODES;
    int sum = 0;
    for (int i = lo; i < hi; ++i) sum += cnt[i];
    s[t] = sum;
    __syncthreads();
    int val = sum;
    for (int o = 1; o < SCAN_T; o <<= 1) {
        int add = (t >= o) ? s[t - o] : 0;
        __syncthreads();
        val += add; s[t] = val;
        __syncthreads();
    }
    int run = val - sum;   // exclusive prefix
    for (int i = lo; i < hi; ++i) {
        off[i] = run; cur[i] = run;
        run += cnt[i];
    }
    if (t == SCAN_T - 1) off[N_NODES] = run;   // t=1023 has empty range -> run = total
}

// ---------------- scatter edge sources into CSR slots
__global__ void k_fill(const int* __restrict__ src, const int* __restrict__ dst,
                       int* __restrict__ cur, int* __restrict__ csr) {
    int e = blockIdx.x * blockDim.x + threadIdx.x;
    if (e < N_EDGES) {
        int d = dst[e];
        int p = atomicAdd(&cur[d], 1);
        csr[p] = src[e];
    }
}

// ---------------- mean aggregation: one wave per node, lane = float2 column
__global__ void k_agg(const float* __restrict__ h, const int* __restrict__ off,
                      const int* __restrict__ csr, float* __restrict__ agg) {
    int gt   = blockIdx.x * blockDim.x + threadIdx.x;
    int node = gt >> 6;
    int lane = gt & 63;
    if (node >= N_NODES) return;
    const float2* hp = (const float2*)h;
    float2*       ap = (float2*)agg;
    int beg = off[node], end = off[node + 1];
    float2 a0 = hp[node * 64 + lane];   // self loop
    float a1x = 0.f, a1y = 0.f;
    int e = beg;
    for (; e + 2 <= end; e += 2) {
        int s0 = csr[e], s1 = csr[e + 1];
        float2 v0 = hp[s0 * 64 + lane];
        float2 v1 = hp[s1 * 64 + lane];
        a0.x += v0.x; a0.y += v0.y;
        a1x  += v1.x; a1y  += v1.y;
    }
    if (e < end) {
        float2 v = hp[csr[e] * 64 + lane];
        a0.x += v.x; a0.y += v.y;
    }
    float inv = 1.0f / (float)(end - beg + 1);
    float2 r; r.x = (a0.x + a1x) * inv; r.y = (a0.y + a1y) * inv;
    ap[node * 64 + lane] = r;
}

// ---------------- fused dual GEMM: out = h@Ws + agg@Wn + (bs+bn), bf16 MFMA
__global__ __launch_bounds__(256) void k_gemm(const float* __restrict__ h,
                                              const float* __restrict__ agg,
                                              const short* __restrict__ bfrag,
                                              const float* __restrict__ biasSum,
                                              float* __restrict__ out) {
    __shared__ short lds[32768];   // 64 KB: self frags [0..16384), neigh [16384..32768)
    {
        const int4* g = (const int4*)bfrag;
        int4* l = (int4*)lds;
        #pragma unroll
        for (int i = 0; i < 16; ++i) l[threadIdx.x + 256 * i] = g[threadIdx.x + 256 * i];
    }
    __syncthreads();
    int wave = threadIdx.x >> 6, lane = threadIdx.x & 63;
    int row0 = blockIdx.x * 64 + wave * 16;
    if (row0 >= N_NODES) return;
    int m = lane & 15, q = lane >> 4;
    const float* hr = h   + (row0 + m) * DIM + q * 8;
    const float* ar = agg + (row0 + m) * DIM + q * 8;
    floatx4 acc[8];
    #pragma unroll
    for (int t = 0; t < 8; ++t) acc[t] = (floatx4){0.f, 0.f, 0.f, 0.f};
    const short* ldsS = lds;
    const short* ldsN = lds + 16384;
    #pragma unroll
    for (int c = 0; c < 4; ++c) {
        float4 h0 = *(const float4*)(hr + c * 32);
        float4 h1 = *(const float4*)(hr + c * 32 + 4);
        float4 a0 = *(const float4*)(ar + c * 32);
        float4 a1 = *(const float4*)(ar + c * 32 + 4);
        short8 ah, aa;
        ah[0]=f2bf(h0.x); ah[1]=f2bf(h0.y); ah[2]=f2bf(h0.z); ah[3]=f2bf(h0.w);
        ah[4]=f2bf(h1.x); ah[5]=f2bf(h1.y); ah[6]=f2bf(h1.z); ah[7]=f2bf(h1.w);
        aa[0]=f2bf(a0.x); aa[1]=f2bf(a0.y); aa[2]=f2bf(a0.z); aa[3]=f2bf(a0.w);
        aa[4]=f2bf(a1.x); aa[5]=f2bf(a1.y); aa[6]=f2bf(a1.z); aa[7]=f2bf(a1.w);
        #pragma unroll
        for (int t = 0; t < 8; ++t) {
            short8 bs = *(const short8*)(ldsS + ((t * 4 + c) * 64 + lane) * 8);
            short8 bn = *(const short8*)(ldsN + ((t * 4 + c) * 64 + lane) * 8);
            acc[t] = __builtin_amdgcn_mfma_f32_16x16x32_bf16(ah, bs, acc[t], 0, 0, 0);
            acc[t] = __builtin_amdgcn_mfma_f32_16x16x32_bf16(aa, bn, acc[t], 0, 0, 0);
        }
    }
    #pragma unroll
    for (int t = 0; t < 8; ++t) {
        float b = biasSum[t * 16 + m];
        #pragma unroll
        for (int r = 0; r < 4; ++r) {
            int row = row0 + q * 4 + r;           // C/D: row = quad*4 + reg
            out[row * DIM + t * 16 + m] = acc[t][r] + b;   // col = t*16 + (lane&15)
        }
    }
}

extern "C" void kernel_launch(void* const* d_in, const int* in_sizes, int n_in,
                              void* d_out, int out_size, void* d_ws, size_t ws_size,
                              hipStream_t stream) {
    const float* h      = (const float*)d_in[0];
    const int*   edges  = (const int*)d_in[1];   // [2, 600000] int32
    const float* Wself  = (const float*)d_in[2];
    const float* bself  = (const float*)d_in[3];
    const float* Wneigh = (const float*)d_in[4];
    const float* bneigh = (const float*)d_in[5];
    float* out = (float*)d_out;
    char*  ws  = (char*)d_ws;

    int*   cnt     = (int*)(ws + WS_CNT);
    int*   off     = (int*)(ws + WS_OFF);
    int*   cur     = (int*)(ws + WS_CUR);
    int*   csr     = (int*)(ws + WS_CSR);
    short* bfrag   = (short*)(ws + WS_BFRAG);
    float* biasSum = (float*)(ws + WS_BIAS);
    float* agg     = (float*)(ws + WS_AGG);

    const int* esrc = edges;
    const int* edst = edges + N_EDGES;

    int prepN = N_NODES + 4096 + DIM;
    k_prep<<<(prepN + 255) / 256, 256, 0, stream>>>(Wself, Wneigh, bself, bneigh,
                                                    cnt, bfrag, biasSum);
    k_count<<<(N_EDGES + 255) / 256, 256, 0, stream>>>(edst, cnt);
    k_scan<<<1, SCAN_T, 0, stream>>>(cnt, off, cur);
    k_fill<<<(N_EDGES + 255) / 256, 256, 0, stream>>>(esrc, edst, cur, csr);
    k_agg<<<(N_NODES * 64 + 255) / 256, 256, 0, stream>>>(h, off, csr, agg);
    k_gemm<<<(N_NODES + 63) / 64, 256, 0, stream>>>(h, agg, bfrag, biasSum, out);
}

// Round 2
// 209.330 us; speedup vs baseline: 1.4740x; 1.4740x over previous
//
#include <hip/hip_runtime.h>
#include <stdint.h>

#define N_NODES 50000
#define N_EDGES 600000
#define DIM 128

// ---- workspace layout (bytes) ----
#define WS_CNT     0            // 50000 * 4
#define WS_OFF     204800       // 50001 * 4
#define WS_CUR     409600       // 50000 * 4
#define WS_CSR     614400       // 600000 * 4
#define WS_BFRAG   3014656      // 2 * 16384 shorts = 65536 B (self, then neigh)
#define WS_BIAS    3080192      // 128 * 4
#define WS_BSUM    3081216      // blockSum: 256 * 4
#define WS_BOFF    3082240      // blockOff: 257 * 4
#define WS_AGG     3084288      // 50000*128*4 = 25.6 MB
// total ~28.7 MB

#define SCAN_NB ((N_NODES + 255) / 256)   // 196 blocks

typedef __attribute__((ext_vector_type(8))) short short8;
typedef __attribute__((ext_vector_type(4))) float floatx4;

__device__ __forceinline__ short f2bf(float f) {
    union { float f; uint32_t u; } x; x.f = f;
    uint32_t r = x.u + 0x7fffu + ((x.u >> 16) & 1u);   // round-to-nearest-even
    return (short)(r >> 16);
}

// ---------------- prep: zero counts, swizzle weights to B-fragment order, bias sum
__global__ void k_prep(const float* __restrict__ Wself,
                       const float* __restrict__ Wneigh,
                       const float* __restrict__ bself,
                       const float* __restrict__ bneigh,
                       int* __restrict__ cnt,
                       short* __restrict__ bfrag,
                       float* __restrict__ biasSum) {
    int id = blockIdx.x * blockDim.x + threadIdx.x;
    if (id < N_NODES) cnt[id] = 0;
    int wid = id - N_NODES;
    if (wid >= 0 && wid < 4096) {
        // fragment layout: ((t*4 + c)*64 + lane)*8 + j  holds  W[c*32 + (lane>>4)*8 + j][t*16 + (lane&15)]
        int w    = wid >> 11;          // 0 = self, 1 = neigh
        int fi   = wid & 2047;
        int lane = fi & 63;
        int tc   = fi >> 6;
        int c    = tc & 3, t = tc >> 2;
        const float* W = w ? Wneigh : Wself;
        int kbase = c * 32 + (lane >> 4) * 8;
        int n     = t * 16 + (lane & 15);
        short* dst = bfrag + (size_t)wid * 8;
        #pragma unroll
        for (int j = 0; j < 8; ++j) dst[j] = f2bf(W[(kbase + j) * DIM + n]);
    }
    int bid = id - N_NODES - 4096;
    if (bid >= 0 && bid < DIM) biasSum[bid] = bself[bid] + bneigh[bid];
}

// ---------------- count in-degree (excluding self loops)
__global__ void k_count(const int* __restrict__ dst, int* __restrict__ cnt) {
    int e = blockIdx.x * blockDim.x + threadIdx.x;
    if (e < N_EDGES) atomicAdd(&cnt[dst[e]], 1);
}

// ---------------- hierarchical scan, phase A: per-block local exclusive scan
__global__ __launch_bounds__(256) void k_scanA(const int* __restrict__ cnt,
                                               int* __restrict__ off,
                                               int* __restrict__ blockSum) {
    __shared__ int s[256];
    int t = threadIdx.x;
    int i = blockIdx.x * 256 + t;
    int v = (i < N_NODES) ? cnt[i] : 0;
    s[t] = v;
    __syncthreads();
    int val = v;
    #pragma unroll
    for (int o = 1; o < 256; o <<= 1) {
        int add = (t >= o) ? s[t - o] : 0;
        __syncthreads();
        val += add; s[t] = val;
        __syncthreads();
    }
    if (i < N_NODES) off[i] = val - v;          // local exclusive
    if (t == 255) blockSum[blockIdx.x] = val;   // block total
}

// ---------------- phase B: single tiny block scans the 196 block sums
__global__ __launch_bounds__(256) void k_scanB(const int* __restrict__ blockSum,
                                               int* __restrict__ blockOff) {
    __shared__ int s[256];
    int t = threadIdx.x;
    int v = (t < SCAN_NB) ? blockSum[t] : 0;
    s[t] = v;
    __syncthreads();
    int val = v;
    #pragma unroll
    for (int o = 1; o < 256; o <<= 1) {
        int add = (t >= o) ? s[t - o] : 0;
        __syncthreads();
        val += add; s[t] = val;
        __syncthreads();
    }
    blockOff[t] = val - v;                       // exclusive
    if (t == SCAN_NB - 1) blockOff[SCAN_NB] = val;   // grand total
}

// ---------------- phase C: apply block offsets, produce off + cur
__global__ __launch_bounds__(256) void k_scanC(int* __restrict__ off,
                                               int* __restrict__ cur,
                                               const int* __restrict__ blockOff) {
    int i = blockIdx.x * 256 + threadIdx.x;
    if (i < N_NODES) {
        int o = off[i] + blockOff[blockIdx.x];
        off[i] = o; cur[i] = o;
    }
    if (i == 0) off[N_NODES] = blockOff[SCAN_NB];
}

// ---------------- scatter edge sources into CSR slots
__global__ void k_fill(const int* __restrict__ src, const int* __restrict__ dst,
                       int* __restrict__ cur, int* __restrict__ csr) {
    int e = blockIdx.x * blockDim.x + threadIdx.x;
    if (e < N_EDGES) {
        int d = dst[e];
        int p = atomicAdd(&cur[d], 1);
        csr[p] = src[e];
    }
}

// ---------------- mean aggregation: one wave per node, lane = float2 column
__global__ void k_agg(const float* __restrict__ h, const int* __restrict__ off,
                      const int* __restrict__ csr, float* __restrict__ agg) {
    int gt   = blockIdx.x * blockDim.x + threadIdx.x;
    int node = gt >> 6;
    int lane = gt & 63;
    if (node >= N_NODES) return;
    const float2* hp = (const float2*)h;
    float2*       ap = (float2*)agg;
    int beg = off[node], end = off[node + 1];
    float2 a0 = hp[node * 64 + lane];   // self loop
    float a1x = 0.f, a1y = 0.f;
    int e = beg;
    for (; e + 2 <= end; e += 2) {
        int s0 = csr[e], s1 = csr[e + 1];
        float2 v0 = hp[s0 * 64 + lane];
        float2 v1 = hp[s1 * 64 + lane];
        a0.x += v0.x; a0.y += v0.y;
        a1x  += v1.x; a1y  += v1.y;
    }
    if (e < end) {
        float2 v = hp[csr[e] * 64 + lane];
        a0.x += v.x; a0.y += v.y;
    }
    float inv = 1.0f / (float)(end - beg + 1);
    float2 r; r.x = (a0.x + a1x) * inv; r.y = (a0.y + a1y) * inv;
    ap[node * 64 + lane] = r;
}

// ---------------- fused dual GEMM: out = h@Ws + agg@Wn + (bs+bn), bf16 MFMA
__global__ __launch_bounds__(256) void k_gemm(const float* __restrict__ h,
                                              const float* __restrict__ agg,
                                              const short* __restrict__ bfrag,
                                              const float* __restrict__ biasSum,
                                              float* __restrict__ out) {
    __shared__ short lds[32768];   // 64 KB: self frags [0..16384), neigh [16384..32768)
    {
        const int4* g = (const int4*)bfrag;
        int4* l = (int4*)lds;
        #pragma unroll
        for (int i = 0; i < 16; ++i) l[threadIdx.x + 256 * i] = g[threadIdx.x + 256 * i];
    }
    __syncthreads();
    int wave = threadIdx.x >> 6, lane = threadIdx.x & 63;
    int row0 = blockIdx.x * 64 + wave * 16;
    if (row0 >= N_NODES) return;
    int m = lane & 15, q = lane >> 4;
    const float* hr = h   + (row0 + m) * DIM + q * 8;
    const float* ar = agg + (row0 + m) * DIM + q * 8;
    floatx4 acc[8];
    #pragma unroll
    for (int t = 0; t < 8; ++t) acc[t] = (floatx4){0.f, 0.f, 0.f, 0.f};
    const short* ldsS = lds;
    const short* ldsN = lds + 16384;
    #pragma unroll
    for (int c = 0; c < 4; ++c) {
        float4 h0 = *(const float4*)(hr + c * 32);
        float4 h1 = *(const float4*)(hr + c * 32 + 4);
        float4 a0 = *(const float4*)(ar + c * 32);
        float4 a1 = *(const float4*)(ar + c * 32 + 4);
        short8 ah, aa;
        ah[0]=f2bf(h0.x); ah[1]=f2bf(h0.y); ah[2]=f2bf(h0.z); ah[3]=f2bf(h0.w);
        ah[4]=f2bf(h1.x); ah[5]=f2bf(h1.y); ah[6]=f2bf(h1.z); ah[7]=f2bf(h1.w);
        aa[0]=f2bf(a0.x); aa[1]=f2bf(a0.y); aa[2]=f2bf(a0.z); aa[3]=f2bf(a0.w);
        aa[4]=f2bf(a1.x); aa[5]=f2bf(a1.y); aa[6]=f2bf(a1.z); aa[7]=f2bf(a1.w);
        #pragma unroll
        for (int t = 0; t < 8; ++t) {
            short8 bs = *(const short8*)(ldsS + ((t * 4 + c) * 64 + lane) * 8);
            short8 bn = *(const short8*)(ldsN + ((t * 4 + c) * 64 + lane) * 8);
            acc[t] = __builtin_amdgcn_mfma_f32_16x16x32_bf16(ah, bs, acc[t], 0, 0, 0);
            acc[t] = __builtin_amdgcn_mfma_f32_16x16x32_bf16(aa, bn, acc[t], 0, 0, 0);
        }
    }
    #pragma unroll
    for (int t = 0; t < 8; ++t) {
        float b = biasSum[t * 16 + m];
        #pragma unroll
        for (int r = 0; r < 4; ++r) {
            int row = row0 + q * 4 + r;           // C/D: row = quad*4 + reg
            out[row * DIM + t * 16 + m] = acc[t][r] + b;   // col = t*16 + (lane&15)
        }
    }
}

extern "C" void kernel_launch(void* const* d_in, const int* in_sizes, int n_in,
                              void* d_out, int out_size, void* d_ws, size_t ws_size,
                              hipStream_t stream) {
    const float* h      = (const float*)d_in[0];
    const int*   edges  = (const int*)d_in[1];   // [2, 600000] int32
    const float* Wself  = (const float*)d_in[2];
    const float* bself  = (const float*)d_in[3];
    const float* Wneigh = (const float*)d_in[4];
    const float* bneigh = (const float*)d_in[5];
    float* out = (float*)d_out;
    char*  ws  = (char*)d_ws;

    int*   cnt      = (int*)(ws + WS_CNT);
    int*   off      = (int*)(ws + WS_OFF);
    int*   cur      = (int*)(ws + WS_CUR);
    int*   csr      = (int*)(ws + WS_CSR);
    short* bfrag    = (short*)(ws + WS_BFRAG);
    float* biasSum  = (float*)(ws + WS_BIAS);
    int*   blockSum = (int*)(ws + WS_BSUM);
    int*   blockOff = (int*)(ws + WS_BOFF);
    float* agg      = (float*)(ws + WS_AGG);

    const int* esrc = edges;
    const int* edst = edges + N_EDGES;

    int prepN = N_NODES + 4096 + DIM;
    k_prep<<<(prepN + 255) / 256, 256, 0, stream>>>(Wself, Wneigh, bself, bneigh,
                                                    cnt, bfrag, biasSum);
    k_count<<<(N_EDGES + 255) / 256, 256, 0, stream>>>(edst, cnt);
    k_scanA<<<SCAN_NB, 256, 0, stream>>>(cnt, off, blockSum);
    k_scanB<<<1, 256, 0, stream>>>(blockSum, blockOff);
    k_scanC<<<SCAN_NB, 256, 0, stream>>>(off, cur, blockOff);
    k_fill<<<(N_EDGES + 255) / 256, 256, 0, stream>>>(esrc, edst, cur, csr);
    k_agg<<<(N_NODES * 64 + 255) / 256, 256, 0, stream>>>(h, off, csr, agg);
    k_gemm<<<(N_NODES + 63) / 64, 256, 0, stream>>>(h, agg, bfrag, biasSum, out);
}

// Round 3
// 199.531 us; speedup vs baseline: 1.5464x; 1.0491x over previous
//
#include <hip/hip_runtime.h>
#include <stdint.h>

#define N_NODES 50000
#define N_EDGES 600000
#define DIM 128

// ---- workspace layout (bytes) ----
#define WS_CNT     0            // 50000 * 4
#define WS_OFF     204800       // 50001 * 4
#define WS_CUR     409600       // 50000 * 4
#define WS_CSR     614400       // 600000 * 4
#define WS_BFRAG   3014656      // 2 * 16384 shorts = 65536 B (self, then neigh)
#define WS_BIAS    3080192      // 128 * 4
#define WS_BSUM    3081216      // blockSum: 256 * 4
#define WS_BOFF    3082240      // blockOff: 257 * 4
#define WS_HB      3084288      // h in bf16: 50000*128*2 = 12.8 MB
#define WS_AGGB    15884288     // agg in bf16: 12.8 MB
// total ~28.7 MB

#define SCAN_NB ((N_NODES + 255) / 256)   // 196 blocks
#define CVT_N   (N_NODES * DIM / 4)       // 1.6M float4-quads

typedef __attribute__((ext_vector_type(8))) short short8;
typedef __attribute__((ext_vector_type(4))) float floatx4;

__device__ __forceinline__ short f2bf(float f) {
    union { float f; uint32_t u; } x; x.f = f;
    uint32_t r = x.u + 0x7fffu + ((x.u >> 16) & 1u);   // round-to-nearest-even
    return (short)(r >> 16);
}
__device__ __forceinline__ float bflo(uint32_t v) {
    union { uint32_t u; float f; } x; x.u = v << 16; return x.f;
}
__device__ __forceinline__ float bfhi(uint32_t v) {
    union { uint32_t u; float f; } x; x.u = v & 0xffff0000u; return x.f;
}
__device__ __forceinline__ uint32_t packbf(float lo, float hi) {
    return (uint32_t)(uint16_t)f2bf(lo) | ((uint32_t)(uint16_t)f2bf(hi) << 16);
}

// ---------------- prep: zero counts, swizzle weights to B-fragment order, bias sum
__global__ void k_prep(const float* __restrict__ Wself,
                       const float* __restrict__ Wneigh,
                       const float* __restrict__ bself,
                       const float* __restrict__ bneigh,
                       int* __restrict__ cnt,
                       short* __restrict__ bfrag,
                       float* __restrict__ biasSum) {
    int id = blockIdx.x * blockDim.x + threadIdx.x;
    if (id < N_NODES) cnt[id] = 0;
    int wid = id - N_NODES;
    if (wid >= 0 && wid < 4096) {
        // fragment layout: ((t*4 + c)*64 + lane)*8 + j  holds  W[c*32 + (lane>>4)*8 + j][t*16 + (lane&15)]
        int w    = wid >> 11;          // 0 = self, 1 = neigh
        int fi   = wid & 2047;
        int lane = fi & 63;
        int tc   = fi >> 6;
        int c    = tc & 3, t = tc >> 2;
        const float* W = w ? Wneigh : Wself;
        int kbase = c * 32 + (lane >> 4) * 8;
        int n     = t * 16 + (lane & 15);
        short* dst = bfrag + (size_t)wid * 8;
        #pragma unroll
        for (int j = 0; j < 8; ++j) dst[j] = f2bf(W[(kbase + j) * DIM + n]);
    }
    int bid = id - N_NODES - 4096;
    if (bid >= 0 && bid < DIM) biasSum[bid] = bself[bid] + bneigh[bid];
}

// ---------------- fused: count in-degree (atomics, latency-bound) + h -> bf16 (BW-bound)
__global__ void k_countcvt(const int* __restrict__ dst, int* __restrict__ cnt,
                           const float4* __restrict__ h4, ushort4* __restrict__ hb4) {
    int id = blockIdx.x * blockDim.x + threadIdx.x;
    if (id < N_EDGES) atomicAdd(&cnt[dst[id]], 1);
    if (id < CVT_N) {
        float4 v = h4[id];
        ushort4 o;
        o.x = (uint16_t)f2bf(v.x); o.y = (uint16_t)f2bf(v.y);
        o.z = (uint16_t)f2bf(v.z); o.w = (uint16_t)f2bf(v.w);
        hb4[id] = o;
    }
}

// ---------------- hierarchical scan, phase A: per-block local exclusive scan
__global__ __launch_bounds__(256) void k_scanA(const int* __restrict__ cnt,
                                               int* __restrict__ off,
                                               int* __restrict__ blockSum) {
    __shared__ int s[256];
    int t = threadIdx.x;
    int i = blockIdx.x * 256 + t;
    int v = (i < N_NODES) ? cnt[i] : 0;
    s[t] = v;
    __syncthreads();
    int val = v;
    #pragma unroll
    for (int o = 1; o < 256; o <<= 1) {
        int add = (t >= o) ? s[t - o] : 0;
        __syncthreads();
        val += add; s[t] = val;
        __syncthreads();
    }
    if (i < N_NODES) off[i] = val - v;          // local exclusive
    if (t == 255) blockSum[blockIdx.x] = val;   // block total
}

// ---------------- phase B: single tiny block scans the 196 block sums
__global__ __launch_bounds__(256) void k_scanB(const int* __restrict__ blockSum,
                                               int* __restrict__ blockOff) {
    __shared__ int s[256];
    int t = threadIdx.x;
    int v = (t < SCAN_NB) ? blockSum[t] : 0;
    s[t] = v;
    __syncthreads();
    int val = v;
    #pragma unroll
    for (int o = 1; o < 256; o <<= 1) {
        int add = (t >= o) ? s[t - o] : 0;
        __syncthreads();
        val += add; s[t] = val;
        __syncthreads();
    }
    blockOff[t] = val - v;                       // exclusive
    if (t == SCAN_NB - 1) blockOff[SCAN_NB] = val;   // grand total
}

// ---------------- phase C: apply block offsets, produce off + cur
__global__ __launch_bounds__(256) void k_scanC(int* __restrict__ off,
                                               int* __restrict__ cur,
                                               const int* __restrict__ blockOff) {
    int i = blockIdx.x * 256 + threadIdx.x;
    if (i < N_NODES) {
        int o = off[i] + blockOff[blockIdx.x];
        off[i] = o; cur[i] = o;
    }
    if (i == 0) off[N_NODES] = blockOff[SCAN_NB];
}

// ---------------- scatter edge sources into CSR slots
__global__ void k_fill(const int* __restrict__ src, const int* __restrict__ dst,
                       int* __restrict__ cur, int* __restrict__ csr) {
    int e = blockIdx.x * blockDim.x + threadIdx.x;
    if (e < N_EDGES) {
        int d = dst[e];
        int p = atomicAdd(&cur[d], 1);
        csr[p] = src[e];
    }
}

// ---------------- mean aggregation on bf16 rows: one wave per node, lane = 2 cols
__global__ void k_agg(const uint32_t* __restrict__ hb, const int* __restrict__ off,
                      const int* __restrict__ csr, uint32_t* __restrict__ aggb) {
    int gt   = blockIdx.x * blockDim.x + threadIdx.x;
    int node = gt >> 6;
    int lane = gt & 63;
    if (node >= N_NODES) return;
    int beg = off[node], end = off[node + 1];
    uint32_t self = hb[node * 64 + lane];   // self loop
    float ax = bflo(self), ay = bfhi(self);
    float bx = 0.f, by = 0.f;
    int e = beg;
    for (; e + 2 <= end; e += 2) {
        int s0 = csr[e], s1 = csr[e + 1];
        uint32_t v0 = hb[s0 * 64 + lane];
        uint32_t v1 = hb[s1 * 64 + lane];
        ax += bflo(v0); ay += bfhi(v0);
        bx += bflo(v1); by += bfhi(v1);
    }
    if (e < end) {
        uint32_t v = hb[csr[e] * 64 + lane];
        ax += bflo(v); ay += bfhi(v);
    }
    float inv = 1.0f / (float)(end - beg + 1);
    aggb[node * 64 + lane] = packbf((ax + bx) * inv, (ay + by) * inv);
}

// ---------------- fused dual GEMM: out = h@Ws + agg@Wn + (bs+bn), bf16 MFMA
__global__ __launch_bounds__(256) void k_gemm(const short* __restrict__ hb,
                                              const short* __restrict__ aggb,
                                              const short* __restrict__ bfrag,
                                              const float* __restrict__ biasSum,
                                              float* __restrict__ out) {
    __shared__ short lds[32768];   // 64 KB: self frags [0..16384), neigh [16384..32768)
    {
        const int4* g = (const int4*)bfrag;
        int4* l = (int4*)lds;
        #pragma unroll
        for (int i = 0; i < 16; ++i) l[threadIdx.x + 256 * i] = g[threadIdx.x + 256 * i];
    }
    __syncthreads();
    int wave = threadIdx.x >> 6, lane = threadIdx.x & 63;
    int row0 = blockIdx.x * 64 + wave * 16;
    if (row0 >= N_NODES) return;
    int m = lane & 15, q = lane >> 4;
    const short* hr = hb   + (row0 + m) * DIM + q * 8;
    const short* ar = aggb + (row0 + m) * DIM + q * 8;
    floatx4 acc[8];
    #pragma unroll
    for (int t = 0; t < 8; ++t) acc[t] = (floatx4){0.f, 0.f, 0.f, 0.f};
    const short* ldsS = lds;
    const short* ldsN = lds + 16384;
    #pragma unroll
    for (int c = 0; c < 4; ++c) {
        short8 ah = *(const short8*)(hr + c * 32);
        short8 aa = *(const short8*)(ar + c * 32);
        #pragma unroll
        for (int t = 0; t < 8; ++t) {
            short8 bs = *(const short8*)(ldsS + ((t * 4 + c) * 64 + lane) * 8);
            short8 bn = *(const short8*)(ldsN + ((t * 4 + c) * 64 + lane) * 8);
            acc[t] = __builtin_amdgcn_mfma_f32_16x16x32_bf16(ah, bs, acc[t], 0, 0, 0);
            acc[t] = __builtin_amdgcn_mfma_f32_16x16x32_bf16(aa, bn, acc[t], 0, 0, 0);
        }
    }
    #pragma unroll
    for (int t = 0; t < 8; ++t) {
        float b = biasSum[t * 16 + m];
        #pragma unroll
        for (int r = 0; r < 4; ++r) {
            int row = row0 + q * 4 + r;           // C/D: row = quad*4 + reg
            out[row * DIM + t * 16 + m] = acc[t][r] + b;   // col = t*16 + (lane&15)
        }
    }
}

extern "C" void kernel_launch(void* const* d_in, const int* in_sizes, int n_in,
                              void* d_out, int out_size, void* d_ws, size_t ws_size,
                              hipStream_t stream) {
    const float* h      = (const float*)d_in[0];
    const int*   edges  = (const int*)d_in[1];   // [2, 600000] int32
    const float* Wself  = (const float*)d_in[2];
    const float* bself  = (const float*)d_in[3];
    const float* Wneigh = (const float*)d_in[4];
    const float* bneigh = (const float*)d_in[5];
    float* out = (float*)d_out;
    char*  ws  = (char*)d_ws;

    int*      cnt      = (int*)(ws + WS_CNT);
    int*      off      = (int*)(ws + WS_OFF);
    int*      cur      = (int*)(ws + WS_CUR);
    int*      csr      = (int*)(ws + WS_CSR);
    short*    bfrag    = (short*)(ws + WS_BFRAG);
    float*    biasSum  = (float*)(ws + WS_BIAS);
    int*      blockSum = (int*)(ws + WS_BSUM);
    int*      blockOff = (int*)(ws + WS_BOFF);
    short*    hb       = (short*)(ws + WS_HB);
    short*    aggb     = (short*)(ws + WS_AGGB);

    const int* esrc = edges;
    const int* edst = edges + N_EDGES;

    int prepN = N_NODES + 4096 + DIM;
    k_prep<<<(prepN + 255) / 256, 256, 0, stream>>>(Wself, Wneigh, bself, bneigh,
                                                    cnt, bfrag, biasSum);
    k_countcvt<<<(CVT_N + 255) / 256, 256, 0, stream>>>(edst, cnt, (const float4*)h,
                                                        (ushort4*)hb);
    k_scanA<<<SCAN_NB, 256, 0, stream>>>(cnt, off, blockSum);
    k_scanB<<<1, 256, 0, stream>>>(blockSum, blockOff);
    k_scanC<<<SCAN_NB, 256, 0, stream>>>(off, cur, blockOff);
    k_fill<<<(N_EDGES + 255) / 256, 256, 0, stream>>>(esrc, edst, cur, csr);
    k_agg<<<(N_NODES * 64 + 255) / 256, 256, 0, stream>>>((const uint32_t*)hb, off, csr,
                                                          (uint32_t*)aggb);
    k_gemm<<<(N_NODES + 63) / 64, 256, 0, stream>>>(hb, aggb, bfrag, biasSum, out);
}

// Round 4
// 188.461 us; speedup vs baseline: 1.6373x; 1.0587x over previous
//
#include <hip/hip_runtime.h>
#include <stdint.h>

#define N_NODES 50000
#define N_EDGES 600000
#define DIM 128

// ---- workspace layout (bytes) ----
#define WS_CNT     0            // 50000 * 4
#define WS_OFF     204800       // 50001 * 4
#define WS_CUR     409600       // 50000 * 4
#define WS_CSR     614400       // 600000 * 4
#define WS_BFRAG   3014656      // 2 * 16384 shorts = 65536 B (self, then neigh)
#define WS_BIAS    3080192      // 128 * 4
#define WS_BSUM    3081216      // blockSum: 256 * 4
#define WS_BOFF    3082240      // blockOff: 257 * 4
#define WS_HB      3084288      // h in bf16: 50000*128*2 = 12.8 MB
#define WS_AGGB    15884288     // agg in bf16: 12.8 MB
// total ~28.7 MB

#define SCAN_NB ((N_NODES + 255) / 256)   // 196 blocks
#define CVT_N   (N_NODES * DIM / 4)       // 1.6M float4-quads

typedef __attribute__((ext_vector_type(8))) short short8;
typedef __attribute__((ext_vector_type(4))) float floatx4;

__device__ __forceinline__ short f2bf(float f) {
    union { float f; uint32_t u; } x; x.f = f;
    uint32_t r = x.u + 0x7fffu + ((x.u >> 16) & 1u);   // round-to-nearest-even
    return (short)(r >> 16);
}
__device__ __forceinline__ float bflo(uint32_t v) {
    union { uint32_t u; float f; } x; x.u = v << 16; return x.f;
}
__device__ __forceinline__ float bfhi(uint32_t v) {
    union { uint32_t u; float f; } x; x.u = v & 0xffff0000u; return x.f;
}
__device__ __forceinline__ uint32_t packbf(float lo, float hi) {
    return (uint32_t)(uint16_t)f2bf(lo) | ((uint32_t)(uint16_t)f2bf(hi) << 16);
}

// ---------------- prep: zero counts, swizzle weights to B-fragment order, bias sum
__global__ void k_prep(const float* __restrict__ Wself,
                       const float* __restrict__ Wneigh,
                       const float* __restrict__ bself,
                       const float* __restrict__ bneigh,
                       int* __restrict__ cnt,
                       short* __restrict__ bfrag,
                       float* __restrict__ biasSum) {
    int id = blockIdx.x * blockDim.x + threadIdx.x;
    if (id < N_NODES) cnt[id] = 0;
    int wid = id - N_NODES;
    if (wid >= 0 && wid < 4096) {
        // fragment layout: ((t*4 + c)*64 + lane)*8 + j  holds  W[c*32 + (lane>>4)*8 + j][t*16 + (lane&15)]
        int w    = wid >> 11;          // 0 = self, 1 = neigh
        int fi   = wid & 2047;
        int lane = fi & 63;
        int tc   = fi >> 6;
        int c    = tc & 3, t = tc >> 2;
        const float* W = w ? Wneigh : Wself;
        int kbase = c * 32 + (lane >> 4) * 8;
        int n     = t * 16 + (lane & 15);
        short* dst = bfrag + (size_t)wid * 8;
        #pragma unroll
        for (int j = 0; j < 8; ++j) dst[j] = f2bf(W[(kbase + j) * DIM + n]);
    }
    int bid = id - N_NODES - 4096;
    if (bid >= 0 && bid < DIM) biasSum[bid] = bself[bid] + bneigh[bid];
}

// ---------------- fused: count in-degree (atomics, latency-bound) + h -> bf16 (BW-bound)
__global__ void k_countcvt(const int* __restrict__ dst, int* __restrict__ cnt,
                           const float4* __restrict__ h4, ushort4* __restrict__ hb4) {
    int id = blockIdx.x * blockDim.x + threadIdx.x;
    if (id < N_EDGES) atomicAdd(&cnt[dst[id]], 1);
    if (id < CVT_N) {
        float4 v = h4[id];
        ushort4 o;
        o.x = (uint16_t)f2bf(v.x); o.y = (uint16_t)f2bf(v.y);
        o.z = (uint16_t)f2bf(v.z); o.w = (uint16_t)f2bf(v.w);
        hb4[id] = o;
    }
}

// ---------------- hierarchical scan, phase A: per-block local exclusive scan
__global__ __launch_bounds__(256) void k_scanA(const int* __restrict__ cnt,
                                               int* __restrict__ off,
                                               int* __restrict__ blockSum) {
    __shared__ int s[256];
    int t = threadIdx.x;
    int i = blockIdx.x * 256 + t;
    int v = (i < N_NODES) ? cnt[i] : 0;
    s[t] = v;
    __syncthreads();
    int val = v;
    #pragma unroll
    for (int o = 1; o < 256; o <<= 1) {
        int add = (t >= o) ? s[t - o] : 0;
        __syncthreads();
        val += add; s[t] = val;
        __syncthreads();
    }
    if (i < N_NODES) off[i] = val - v;          // local exclusive
    if (t == 255) blockSum[blockIdx.x] = val;   // block total
}

// ---------------- phase B: single tiny block scans the 196 block sums
__global__ __launch_bounds__(256) void k_scanB(const int* __restrict__ blockSum,
                                               int* __restrict__ blockOff) {
    __shared__ int s[256];
    int t = threadIdx.x;
    int v = (t < SCAN_NB) ? blockSum[t] : 0;
    s[t] = v;
    __syncthreads();
    int val = v;
    #pragma unroll
    for (int o = 1; o < 256; o <<= 1) {
        int add = (t >= o) ? s[t - o] : 0;
        __syncthreads();
        val += add; s[t] = val;
        __syncthreads();
    }
    blockOff[t] = val - v;                       // exclusive
    if (t == SCAN_NB - 1) blockOff[SCAN_NB] = val;   // grand total
}

// ---------------- phase C: apply block offsets, produce off + cur
__global__ __launch_bounds__(256) void k_scanC(int* __restrict__ off,
                                               int* __restrict__ cur,
                                               const int* __restrict__ blockOff) {
    int i = blockIdx.x * 256 + threadIdx.x;
    if (i < N_NODES) {
        int o = off[i] + blockOff[blockIdx.x];
        off[i] = o; cur[i] = o;
    }
    if (i == 0) off[N_NODES] = blockOff[SCAN_NB];
}

// ---------------- scatter edge sources into CSR slots
__global__ void k_fill(const int* __restrict__ src, const int* __restrict__ dst,
                       int* __restrict__ cur, int* __restrict__ csr) {
    int e = blockIdx.x * blockDim.x + threadIdx.x;
    if (e < N_EDGES) {
        int d = dst[e];
        int p = atomicAdd(&cur[d], 1);
        csr[p] = src[e];
    }
}

// ---------------- mean aggregation: one wave per node, quarter-wave = one edge,
// lane loads uint4 (16B = 8 bf16 cols). One gather instruction covers 4 edge rows (1KB).
__global__ void k_agg(const uint4* __restrict__ hb4, const int* __restrict__ off,
                      const int* __restrict__ csr, uint4* __restrict__ aggb4) {
    int gt   = blockIdx.x * blockDim.x + threadIdx.x;
    int node = gt >> 6;
    if (node >= N_NODES) return;
    int lane = threadIdx.x & 63;
    int q = lane >> 4;          // quarter: which edge in the group of 4
    int c = lane & 15;          // col group: 8 bf16 cols = one uint4 (row = 16 uint4)
    int beg = off[node], end = off[node + 1];

    float a0=0.f,a1=0.f,a2=0.f,a3=0.f,a4=0.f,a5=0.f,a6=0.f,a7=0.f;
    for (int e = beg + q; e < end; e += 4) {
        int s = csr[e];
        uint4 v = hb4[(size_t)s * 16 + c];
        a0 += bflo(v.x); a1 += bfhi(v.x);
        a2 += bflo(v.y); a3 += bfhi(v.y);
        a4 += bflo(v.z); a5 += bfhi(v.z);
        a6 += bflo(v.w); a7 += bfhi(v.w);
    }
    // combine the 4 quarter-wave partials (lanes c, c+16, c+32, c+48 hold same cols)
    a0 += __shfl_xor(a0, 16, 64); a0 += __shfl_xor(a0, 32, 64);
    a1 += __shfl_xor(a1, 16, 64); a1 += __shfl_xor(a1, 32, 64);
    a2 += __shfl_xor(a2, 16, 64); a2 += __shfl_xor(a2, 32, 64);
    a3 += __shfl_xor(a3, 16, 64); a3 += __shfl_xor(a3, 32, 64);
    a4 += __shfl_xor(a4, 16, 64); a4 += __shfl_xor(a4, 32, 64);
    a5 += __shfl_xor(a5, 16, 64); a5 += __shfl_xor(a5, 32, 64);
    a6 += __shfl_xor(a6, 16, 64); a6 += __shfl_xor(a6, 32, 64);
    a7 += __shfl_xor(a7, 16, 64); a7 += __shfl_xor(a7, 32, 64);
    // self loop (same value added on all lanes -> stays quarter-consistent)
    uint4 sv = hb4[(size_t)node * 16 + c];
    a0 += bflo(sv.x); a1 += bfhi(sv.x);
    a2 += bflo(sv.y); a3 += bfhi(sv.y);
    a4 += bflo(sv.z); a5 += bfhi(sv.z);
    a6 += bflo(sv.w); a7 += bfhi(sv.w);
    float inv = 1.0f / (float)(end - beg + 1);
    if (q == 0) {
        uint4 o;
        o.x = packbf(a0 * inv, a1 * inv);
        o.y = packbf(a2 * inv, a3 * inv);
        o.z = packbf(a4 * inv, a5 * inv);
        o.w = packbf(a6 * inv, a7 * inv);
        aggb4[(size_t)node * 16 + c] = o;
    }
}

// ---------------- fused dual GEMM: out = h@Ws + agg@Wn + (bs+bn), bf16 MFMA
__global__ __launch_bounds__(256) void k_gemm(const short* __restrict__ hb,
                                              const short* __restrict__ aggb,
                                              const short* __restrict__ bfrag,
                                              const float* __restrict__ biasSum,
                                              float* __restrict__ out) {
    __shared__ short lds[32768];   // 64 KB: self frags [0..16384), neigh [16384..32768)
    {
        const int4* g = (const int4*)bfrag;
        int4* l = (int4*)lds;
        #pragma unroll
        for (int i = 0; i < 16; ++i) l[threadIdx.x + 256 * i] = g[threadIdx.x + 256 * i];
    }
    __syncthreads();
    int wave = threadIdx.x >> 6, lane = threadIdx.x & 63;
    int row0 = blockIdx.x * 64 + wave * 16;
    if (row0 >= N_NODES) return;
    int m = lane & 15, q = lane >> 4;
    const short* hr = hb   + (row0 + m) * DIM + q * 8;
    const short* ar = aggb + (row0 + m) * DIM + q * 8;
    floatx4 acc[8];
    #pragma unroll
    for (int t = 0; t < 8; ++t) acc[t] = (floatx4){0.f, 0.f, 0.f, 0.f};
    const short* ldsS = lds;
    const short* ldsN = lds + 16384;
    #pragma unroll
    for (int c = 0; c < 4; ++c) {
        short8 ah = *(const short8*)(hr + c * 32);
        short8 aa = *(const short8*)(ar + c * 32);
        #pragma unroll
        for (int t = 0; t < 8; ++t) {
            short8 bs = *(const short8*)(ldsS + ((t * 4 + c) * 64 + lane) * 8);
            short8 bn = *(const short8*)(ldsN + ((t * 4 + c) * 64 + lane) * 8);
            acc[t] = __builtin_amdgcn_mfma_f32_16x16x32_bf16(ah, bs, acc[t], 0, 0, 0);
            acc[t] = __builtin_amdgcn_mfma_f32_16x16x32_bf16(aa, bn, acc[t], 0, 0, 0);
        }
    }
    #pragma unroll
    for (int t = 0; t < 8; ++t) {
        float b = biasSum[t * 16 + m];
        #pragma unroll
        for (int r = 0; r < 4; ++r) {
            int row = row0 + q * 4 + r;           // C/D: row = quad*4 + reg
            out[row * DIM + t * 16 + m] = acc[t][r] + b;   // col = t*16 + (lane&15)
        }
    }
}

extern "C" void kernel_launch(void* const* d_in, const int* in_sizes, int n_in,
                              void* d_out, int out_size, void* d_ws, size_t ws_size,
                              hipStream_t stream) {
    const float* h      = (const float*)d_in[0];
    const int*   edges  = (const int*)d_in[1];   // [2, 600000] int32
    const float* Wself  = (const float*)d_in[2];
    const float* bself  = (const float*)d_in[3];
    const float* Wneigh = (const float*)d_in[4];
    const float* bneigh = (const float*)d_in[5];
    float* out = (float*)d_out;
    char*  ws  = (char*)d_ws;

    int*      cnt      = (int*)(ws + WS_CNT);
    int*      off      = (int*)(ws + WS_OFF);
    int*      cur      = (int*)(ws + WS_CUR);
    int*      csr      = (int*)(ws + WS_CSR);
    short*    bfrag    = (short*)(ws + WS_BFRAG);
    float*    biasSum  = (float*)(ws + WS_BIAS);
    int*      blockSum = (int*)(ws + WS_BSUM);
    int*      blockOff = (int*)(ws + WS_BOFF);
    short*    hb       = (short*)(ws + WS_HB);
    short*    aggb     = (short*)(ws + WS_AGGB);

    const int* esrc = edges;
    const int* edst = edges + N_EDGES;

    int prepN = N_NODES + 4096 + DIM;
    k_prep<<<(prepN + 255) / 256, 256, 0, stream>>>(Wself, Wneigh, bself, bneigh,
                                                    cnt, bfrag, biasSum);
    k_countcvt<<<(CVT_N + 255) / 256, 256, 0, stream>>>(edst, cnt, (const float4*)h,
                                                        (ushort4*)hb);
    k_scanA<<<SCAN_NB, 256, 0, stream>>>(cnt, off, blockSum);
    k_scanB<<<1, 256, 0, stream>>>(blockSum, blockOff);
    k_scanC<<<SCAN_NB, 256, 0, stream>>>(off, cur, blockOff);
    k_fill<<<(N_EDGES + 255) / 256, 256, 0, stream>>>(esrc, edst, cur, csr);
    k_agg<<<(N_NODES * 64 + 255) / 256, 256, 0, stream>>>((const uint4*)hb, off, csr,
                                                          (uint4*)aggb);
    k_gemm<<<(N_NODES + 63) / 64, 256, 0, stream>>>(hb, aggb, bfrag, biasSum, out);
}